// Round 1
// baseline (1942.236 us; speedup 1.0000x reference)
//
#include <hip/hip_runtime.h>

// GraphSAGE_GAT: SAGE(mean)x2 -> GAT(2 heads, softmax) -> edge MLP
// N=100000 nodes, E=1600000 edges, D=32, H=2, EF=16. All fp32.

#define DD 32
#define HH 2
#define EFF 16

__device__ __forceinline__ unsigned f2o(float f) {
    unsigned u = __float_as_uint(f);
    return (u & 0x80000000u) ? ~u : (u | 0x80000000u);
}
__device__ __forceinline__ float o2f(unsigned u) {
    return (u & 0x80000000u) ? __uint_as_float(u & 0x7fffffffu) : __uint_as_float(~u);
}
__device__ __forceinline__ float lrelu(float x) { return x > 0.f ? x : 0.2f * x; }

// ---- SAGE: scatter-sum x[src] into agg[dst], count edges per dst ----
__global__ void sage_agg_k(const float* __restrict__ x, const int* __restrict__ src,
                           const int* __restrict__ dst, float* __restrict__ agg,
                           float* __restrict__ cnt, int E) {
    int gid = blockIdx.x * blockDim.x + threadIdx.x;
    int e = gid >> 5;
    if (e >= E) return;
    int k = gid & 31;
    int s = src[e], d = dst[e];
    atomicAdd(&agg[d * DD + k], x[s * DD + k]);
    if (k == 0) atomicAdd(&cnt[d], 1.0f);
}

// ---- SAGE: out = relu(mean @ wl + bl + x @ wr) ----
__global__ void sage_update_k(const float* __restrict__ x, const float* __restrict__ agg,
                              const float* __restrict__ cnt, const float* __restrict__ wl,
                              const float* __restrict__ bl, const float* __restrict__ wr,
                              float* __restrict__ out, int N) {
    __shared__ float s_wl[DD * DD];
    __shared__ float s_wr[DD * DD];
    __shared__ float s_b[DD];
    for (int i = threadIdx.x; i < DD * DD; i += blockDim.x) {
        s_wl[i] = wl[i];
        s_wr[i] = wr[i];
    }
    if (threadIdx.x < DD) s_b[threadIdx.x] = bl[threadIdx.x];
    __syncthreads();
    int gid = blockIdx.x * blockDim.x + threadIdx.x;
    int n = gid >> 5;
    if (n >= N) return;
    int k = gid & 31;
    float inv = 1.0f / fmaxf(cnt[n], 1.0f);
    const float* ar = agg + n * DD;
    const float* xr = x + n * DD;
    float acc = s_b[k];
#pragma unroll
    for (int i = 0; i < DD; i++) {
        acc += (ar[i] * inv) * s_wl[i * DD + k];
        acc += xr[i] * s_wr[i * DD + k];
    }
    out[n * DD + k] = fmaxf(acc, 0.f);
}

// ---- GAT: xh = x @ gat_w   ([N,32] @ [32,64] -> [N,64]) ----
__global__ void gat_xh_k(const float* __restrict__ x, const float* __restrict__ w,
                         float* __restrict__ xh, int N) {
    __shared__ float s_w[DD * HH * DD];  // 32x64
    for (int i = threadIdx.x; i < DD * HH * DD; i += blockDim.x) s_w[i] = w[i];
    __syncthreads();
    int gid = blockIdx.x * blockDim.x + threadIdx.x;
    int n = gid >> 6;
    if (n >= N) return;
    int j = gid & 63;
    const float* xr = x + n * DD;
    float acc = 0.f;
#pragma unroll
    for (int i = 0; i < DD; i++) acc += xr[i] * s_w[i * (HH * DD) + j];
    xh[n * (HH * DD) + j] = acc;
}

// ---- GAT: per-node attention scores a_s, a_d  [N,H] ----
__global__ void gat_scores_k(const float* __restrict__ xh, const float* __restrict__ att_src,
                             const float* __restrict__ att_dst, float* __restrict__ a_s,
                             float* __restrict__ a_d, int N) {
    int gid = blockIdx.x * blockDim.x + threadIdx.x;
    int n = gid >> 1;
    if (n >= N) return;
    int h = gid & 1;
    const float* xr = xh + n * (HH * DD) + h * DD;
    float as = 0.f, ad = 0.f;
#pragma unroll
    for (int i = 0; i < DD; i++) {
        as += xr[i] * att_src[h * DD + i];
        ad += xr[i] * att_dst[h * DD + i];
    }
    a_s[n * HH + h] = as;
    a_d[n * HH + h] = ad;
}

// ---- GAT: segment max of alpha over dst (incl. self loops) ----
__global__ void gat_max_k(const float* __restrict__ a_s, const float* __restrict__ a_d,
                          const int* __restrict__ src, const int* __restrict__ dst,
                          unsigned* __restrict__ m, int E, int N) {
    int gid = blockIdx.x * blockDim.x + threadIdx.x;
    if (gid >= E + N) return;
    int s, d;
    if (gid < E) { s = src[gid]; d = dst[gid]; } else { s = d = gid - E; }
    float al0 = lrelu(a_s[s * 2 + 0] + a_d[d * 2 + 0]);
    float al1 = lrelu(a_s[s * 2 + 1] + a_d[d * 2 + 1]);
    atomicMax(&m[d * 2 + 0], f2o(al0));
    atomicMax(&m[d * 2 + 1], f2o(al1));
}

// ---- GAT: denominator  den[d,h] = sum exp(alpha - m[d,h]) ----
__global__ void gat_den_k(const float* __restrict__ a_s, const float* __restrict__ a_d,
                          const int* __restrict__ src, const int* __restrict__ dst,
                          const unsigned* __restrict__ m, float* __restrict__ den, int E, int N) {
    int gid = blockIdx.x * blockDim.x + threadIdx.x;
    if (gid >= E + N) return;
    int s, d;
    if (gid < E) { s = src[gid]; d = dst[gid]; } else { s = d = gid - E; }
    float al0 = lrelu(a_s[s * 2 + 0] + a_d[d * 2 + 0]);
    float al1 = lrelu(a_s[s * 2 + 1] + a_d[d * 2 + 1]);
    atomicAdd(&den[d * 2 + 0], expf(al0 - o2f(m[d * 2 + 0])));
    atomicAdd(&den[d * 2 + 1], expf(al1 - o2f(m[d * 2 + 1])));
}

// ---- GAT: weighted scatter-sum of xh[src] into acc[dst] ----
__global__ void gat_acc_k(const float* __restrict__ xh, const float* __restrict__ a_s,
                          const float* __restrict__ a_d, const int* __restrict__ src,
                          const int* __restrict__ dst, const unsigned* __restrict__ m,
                          const float* __restrict__ den, float* __restrict__ acc, int E, int N) {
    int gid = blockIdx.x * blockDim.x + threadIdx.x;
    int e = gid >> 5;
    if (e >= E + N) return;
    int k = gid & 31;
    int s, d;
    if (e < E) { s = src[e]; d = dst[e]; } else { s = d = e - E; }
    float al0 = lrelu(a_s[s * 2 + 0] + a_d[d * 2 + 0]);
    float al1 = lrelu(a_s[s * 2 + 1] + a_d[d * 2 + 1]);
    float w0 = expf(al0 - o2f(m[d * 2 + 0])) / (den[d * 2 + 0] + 1e-16f);
    float w1 = expf(al1 - o2f(m[d * 2 + 1])) / (den[d * 2 + 1] + 1e-16f);
    atomicAdd(&acc[d * (HH * DD) + k], xh[s * (HH * DD) + k] * w0);
    atomicAdd(&acc[d * (HH * DD) + DD + k], xh[s * (HH * DD) + DD + k] * w1);
}

// ---- GAT: out = relu(mean over heads + bias) ----
__global__ void gat_out_k(const float* __restrict__ acc, const float* __restrict__ bias,
                          float* __restrict__ out, int N) {
    int gid = blockIdx.x * blockDim.x + threadIdx.x;
    int n = gid >> 5;
    if (n >= N) return;
    int k = gid & 31;
    float v = 0.5f * (acc[n * (HH * DD) + k] + acc[n * (HH * DD) + DD + k]) + bias[k];
    out[n * DD + k] = fmaxf(v, 0.f);
}

// ---- Edge MLP: out[e] = relu([x[s],x[d],ea] @ w1 + b1) @ w2 + b2 ----
__global__ void edge_mlp_k(const float* __restrict__ x3, const float* __restrict__ eattr,
                           const int* __restrict__ src, const int* __restrict__ dst,
                           const float* __restrict__ w1, const float* __restrict__ b1,
                           const float* __restrict__ w2, const float* __restrict__ b2,
                           float* __restrict__ out, int E) {
    __shared__ float s_w1[(2 * DD + EFF) * 32];
    __shared__ float s_b1[32];
    __shared__ float s_w2[32];
    for (int i = threadIdx.x; i < (2 * DD + EFF) * 32; i += blockDim.x) s_w1[i] = w1[i];
    if (threadIdx.x < 32) {
        s_b1[threadIdx.x] = b1[threadIdx.x];
        s_w2[threadIdx.x] = w2[threadIdx.x];
    }
    __syncthreads();
    int gid = blockIdx.x * blockDim.x + threadIdx.x;
    int e = gid >> 5;
    if (e >= E) return;
    int k = gid & 31;
    int s = src[e], d = dst[e];
    const float* xs = x3 + s * DD;
    const float* xd = x3 + d * DD;
    const float* ea = eattr + e * EFF;
    float acc = s_b1[k];
#pragma unroll
    for (int i = 0; i < DD; i++) acc += xs[i] * s_w1[i * 32 + k];
#pragma unroll
    for (int i = 0; i < DD; i++) acc += xd[i] * s_w1[(DD + i) * 32 + k];
#pragma unroll
    for (int i = 0; i < EFF; i++) acc += ea[i] * s_w1[(2 * DD + i) * 32 + k];
    acc = fmaxf(acc, 0.f);
    float p = acc * s_w2[k];
#pragma unroll
    for (int off = 16; off > 0; off >>= 1) p += __shfl_down(p, off, 32);
    if (k == 0) out[e] = p + b2[0];
}

extern "C" void kernel_launch(void* const* d_in, const int* in_sizes, int n_in,
                              void* d_out, int out_size, void* d_ws, size_t ws_size,
                              hipStream_t stream) {
    const int E = in_sizes[0] / 2;
    const int N = in_sizes[2] / DD;

    const int* src = (const int*)d_in[0];
    const int* dst = src + E;
    const float* edge_attr = (const float*)d_in[1];
    const float* node_emb = (const float*)d_in[2];
    const float* sage1_wl = (const float*)d_in[3];
    const float* sage1_bl = (const float*)d_in[4];
    const float* sage1_wr = (const float*)d_in[5];
    const float* sage2_wl = (const float*)d_in[6];
    const float* sage2_bl = (const float*)d_in[7];
    const float* sage2_wr = (const float*)d_in[8];
    const float* gat_w = (const float*)d_in[9];
    const float* gat_att_src = (const float*)d_in[10];
    const float* gat_att_dst = (const float*)d_in[11];
    const float* gat_bias = (const float*)d_in[12];
    const float* mlp_w1 = (const float*)d_in[13];
    const float* mlp_b1 = (const float*)d_in[14];
    const float* mlp_w2 = (const float*)d_in[15];
    const float* mlp_b2 = (const float*)d_in[16];
    float* out = (float*)d_out;

    // Workspace layout (floats)
    float* ws = (float*)d_ws;
    float* bufA = ws;                          // 64N: agg (first 32N), later xh
    float* bufB = bufA + (size_t)64 * N;       // 32N: x1, later x3
    float* bufC = bufB + (size_t)32 * N;       // 32N: x2
    float* bufAcc = bufC + (size_t)32 * N;     // 64N: GAT accumulator
    float* cnt = bufAcc + (size_t)64 * N;      // N
    float* a_s = cnt + N;                      // 2N
    float* a_d = a_s + (size_t)2 * N;          // 2N
    unsigned* mbuf = (unsigned*)(a_d + (size_t)2 * N);  // 2N
    float* den = (float*)mbuf + (size_t)2 * N;          // 2N

    const int BS = 256;
    const int gE32 = (E * 32 + BS - 1) / BS;
    const int gN32 = (N * 32 + BS - 1) / BS;
    const int gN64 = (N * 64 + BS - 1) / BS;
    const int gE2 = (E + N + BS - 1) / BS;
    const int gE2x32 = ((E + N) * 32 + BS - 1) / BS;
    const int gN2 = (N * 2 + BS - 1) / BS;

    // ---- SAGE layer 1 ----
    hipMemsetAsync(bufA, 0, (size_t)32 * N * sizeof(float), stream);
    hipMemsetAsync(cnt, 0, (size_t)N * sizeof(float), stream);
    sage_agg_k<<<gE32, BS, 0, stream>>>(node_emb, src, dst, bufA, cnt, E);
    sage_update_k<<<gN32, BS, 0, stream>>>(node_emb, bufA, cnt, sage1_wl, sage1_bl, sage1_wr,
                                           bufB, N);
    // ---- SAGE layer 2 ----
    hipMemsetAsync(bufA, 0, (size_t)32 * N * sizeof(float), stream);
    hipMemsetAsync(cnt, 0, (size_t)N * sizeof(float), stream);
    sage_agg_k<<<gE32, BS, 0, stream>>>(bufB, src, dst, bufA, cnt, E);
    sage_update_k<<<gN32, BS, 0, stream>>>(bufB, bufA, cnt, sage2_wl, sage2_bl, sage2_wr,
                                           bufC, N);
    // ---- GAT ----
    gat_xh_k<<<gN64, BS, 0, stream>>>(bufC, gat_w, bufA, N);  // bufA = xh [N,64]
    gat_scores_k<<<gN2, BS, 0, stream>>>(bufA, gat_att_src, gat_att_dst, a_s, a_d, N);
    hipMemsetAsync(mbuf, 0, (size_t)2 * N * sizeof(unsigned), stream);
    hipMemsetAsync(den, 0, (size_t)2 * N * sizeof(float), stream);
    hipMemsetAsync(bufAcc, 0, (size_t)64 * N * sizeof(float), stream);
    gat_max_k<<<gE2, BS, 0, stream>>>(a_s, a_d, src, dst, mbuf, E, N);
    gat_den_k<<<gE2, BS, 0, stream>>>(a_s, a_d, src, dst, mbuf, den, E, N);
    gat_acc_k<<<gE2x32, BS, 0, stream>>>(bufA, a_s, a_d, src, dst, mbuf, den, bufAcc, E, N);
    gat_out_k<<<gN32, BS, 0, stream>>>(bufAcc, gat_bias, bufB, N);  // bufB = x3

    // ---- Edge MLP ----
    edge_mlp_k<<<gE32, BS, 0, stream>>>(bufB, edge_attr, src, dst, mlp_w1, mlp_b1, mlp_w2,
                                        mlp_b2, out, E);
}

// Round 2
// 932.255 us; speedup vs baseline: 2.0834x; 2.0834x over previous
//
#include <hip/hip_runtime.h>

// GraphSAGE_GAT: SAGE(mean)x2 -> GAT(2 heads, softmax) -> edge MLP
// N=100000 nodes, E=1600000 edges, D=32, H=2, EF=16. All fp32.
// R2: CSR-by-dst (hist+scan+fill) -> gather-side aggregation, zero f32 atomics.
//     GAT online-softmax single pass. Edge MLP one-edge-per-lane, LDS weights.

#define DD 32
#define HH 2
#define EFF 16

__device__ __forceinline__ float lrelu(float x) { return x > 0.f ? x : 0.2f * x; }

// ---- CSR build: histogram of dst ----
__global__ void hist_k(const int* __restrict__ dst, int* __restrict__ deg, int E) {
    int e = blockIdx.x * blockDim.x + threadIdx.x;
    if (e < E) atomicAdd(&deg[dst[e]], 1);
}

// ---- CSR build: single-block exclusive scan (N=100K) ----
__global__ void scan_k(const int* __restrict__ deg, int* __restrict__ rowptr, int N) {
    __shared__ int s_part[1024];
    int t = threadIdx.x;
    int chunk = (N + 1023) / 1024;
    int lo = t * chunk, hi = min(lo + chunk, N);
    int sum = 0;
    for (int i = lo; i < hi; i++) sum += deg[i];
    s_part[t] = sum;
    __syncthreads();
    // Hillis-Steele inclusive scan over the 1024 partials
    for (int off = 1; off < 1024; off <<= 1) {
        int v = (t >= off) ? s_part[t - off] : 0;
        __syncthreads();
        s_part[t] += v;
        __syncthreads();
    }
    int base = (t == 0) ? 0 : s_part[t - 1];
    for (int i = lo; i < hi; i++) { rowptr[i] = base; base += deg[i]; }
    if (t == 1023) rowptr[N] = base;  // = E
}

// ---- CSR build: scatter src ids into per-dst buckets ----
__global__ void fill_k(const int* __restrict__ src, const int* __restrict__ dst,
                       const int* __restrict__ rowptr, int* __restrict__ fill,
                       int* __restrict__ csr_src, int E) {
    int e = blockIdx.x * blockDim.x + threadIdx.x;
    if (e >= E) return;
    int d = dst[e];
    int pos = rowptr[d] + atomicAdd(&fill[d], 1);
    csr_src[pos] = src[e];
}

// ---- SAGE fused: gather-mean over incoming edges + lin_l + lin_r + relu ----
// one 32-lane group per node
__global__ void sage_fused_k(const float* __restrict__ x, const int* __restrict__ rowptr,
                             const int* __restrict__ csr_src, const float* __restrict__ wl,
                             const float* __restrict__ bl, const float* __restrict__ wr,
                             float* __restrict__ out, int N) {
    __shared__ float s_wl[DD * DD];
    __shared__ float s_wr[DD * DD];
    __shared__ float s_b[DD];
    for (int i = threadIdx.x; i < DD * DD; i += blockDim.x) {
        s_wl[i] = wl[i];
        s_wr[i] = wr[i];
    }
    if (threadIdx.x < DD) s_b[threadIdx.x] = bl[threadIdx.x];
    __syncthreads();
    int gid = blockIdx.x * blockDim.x + threadIdx.x;
    int n = gid >> 5;
    if (n >= N) return;
    int k = gid & 31;
    int lo = rowptr[n], hi = rowptr[n + 1];
    float acc = 0.f;
    for (int j = lo; j < hi; j++) {
        int s = csr_src[j];  // broadcast within group
        acc += x[(size_t)s * DD + k];
    }
    float inv = 1.0f / fmaxf((float)(hi - lo), 1.0f);
    float mean = acc * inv;
    float xv = x[(size_t)n * DD + k];
    float o = s_b[k];
#pragma unroll
    for (int i = 0; i < DD; i++) {
        o += __shfl(mean, i, 32) * s_wl[i * DD + k];
        o += __shfl(xv, i, 32) * s_wr[i * DD + k];
    }
    out[(size_t)n * DD + k] = fmaxf(o, 0.f);
}

// ---- GAT: xh = x @ gat_w   ([N,32] @ [32,64] -> [N,64]) ----
__global__ void gat_xh_k(const float* __restrict__ x, const float* __restrict__ w,
                         float* __restrict__ xh, int N) {
    __shared__ float s_w[DD * HH * DD];  // 32x64
    for (int i = threadIdx.x; i < DD * HH * DD; i += blockDim.x) s_w[i] = w[i];
    __syncthreads();
    int gid = blockIdx.x * blockDim.x + threadIdx.x;
    int n = gid >> 6;
    if (n >= N) return;
    int j = gid & 63;
    const float* xr = x + (size_t)n * DD;
    float acc = 0.f;
#pragma unroll
    for (int i = 0; i < DD; i++) acc += xr[i] * s_w[i * (HH * DD) + j];
    xh[(size_t)n * (HH * DD) + j] = acc;
}

// ---- GAT: per-node attention scores a_s, a_d  [N,H] ----
__global__ void gat_scores_k(const float* __restrict__ xh, const float* __restrict__ att_src,
                             const float* __restrict__ att_dst, float* __restrict__ a_s,
                             float* __restrict__ a_d, int N) {
    int gid = blockIdx.x * blockDim.x + threadIdx.x;
    int n = gid >> 1;
    if (n >= N) return;
    int h = gid & 1;
    const float* xr = xh + (size_t)n * (HH * DD) + h * DD;
    float as = 0.f, ad = 0.f;
#pragma unroll
    for (int i = 0; i < DD; i++) {
        as += xr[i] * att_src[h * DD + i];
        ad += xr[i] * att_dst[h * DD + i];
    }
    a_s[n * HH + h] = as;
    a_d[n * HH + h] = ad;
}

// ---- GAT fused: online softmax over incoming edges (+self loop), one wave/node ----
__global__ void gat_fused_k(const float* __restrict__ xh, const float* __restrict__ a_s,
                            const float* __restrict__ a_d, const int* __restrict__ rowptr,
                            const int* __restrict__ csr_src, const float* __restrict__ bias,
                            float* __restrict__ out, int N) {
    int gid = blockIdx.x * blockDim.x + threadIdx.x;
    int n = gid >> 6;
    if (n >= N) return;
    int l = gid & 63;
    int h = l >> 5, kk = l & 31;
    float ad = a_d[n * HH + h];
    // self loop (alpha = a_s[n] + a_d[n])
    float m = lrelu(a_s[n * HH + h] + ad);
    float den = 1.f;
    float acc = xh[(size_t)n * (HH * DD) + l];
    int lo = rowptr[n], hi = rowptr[n + 1];
    for (int j = lo; j < hi; j++) {
        int s = csr_src[j];
        float alpha = lrelu(a_s[s * HH + h] + ad);
        float nm = fmaxf(m, alpha);
        float scale = __expf(m - nm);
        float w = __expf(alpha - nm);
        den = den * scale + w;
        acc = acc * scale + w * xh[(size_t)s * (HH * DD) + l];
        m = nm;
    }
    float v = acc / (den + 1e-16f);
    float o = 0.5f * (v + __shfl_xor(v, 32, 64));
    if (h == 0) out[(size_t)n * DD + kk] = fmaxf(o + bias[kk], 0.f);
}

// ---- Edge MLP v2: one edge per lane; weights broadcast from LDS ----
__device__ __forceinline__ void mlp_chunk(float4 v, const float* __restrict__ wbase,
                                          float acc[DD]) {
    const float va[4] = {v.x, v.y, v.z, v.w};
#pragma unroll
    for (int r = 0; r < 4; r++) {
#pragma unroll
        for (int j4 = 0; j4 < 8; j4++) {
            const float4 w = *(const float4*)(wbase + r * DD + j4 * 4);
            acc[j4 * 4 + 0] += va[r] * w.x;
            acc[j4 * 4 + 1] += va[r] * w.y;
            acc[j4 * 4 + 2] += va[r] * w.z;
            acc[j4 * 4 + 3] += va[r] * w.w;
        }
    }
}

__global__ void edge_mlp_v2(const float* __restrict__ x3, const float* __restrict__ eattr,
                            const int* __restrict__ src, const int* __restrict__ dst,
                            const float* __restrict__ w1, const float* __restrict__ b1,
                            const float* __restrict__ w2, const float* __restrict__ b2,
                            float* __restrict__ out, int E) {
    __shared__ float s_w1[(2 * DD + EFF) * DD];  // 80 x 32
    __shared__ float s_b1[DD];
    __shared__ float s_w2[DD];
    for (int i = threadIdx.x; i < (2 * DD + EFF) * DD; i += blockDim.x) s_w1[i] = w1[i];
    if (threadIdx.x < DD) {
        s_b1[threadIdx.x] = b1[threadIdx.x];
        s_w2[threadIdx.x] = w2[threadIdx.x];
    }
    __syncthreads();
    int e = blockIdx.x * blockDim.x + threadIdx.x;
    if (e >= E) return;
    float b2v = b2[0];
    int s = src[e], d = dst[e];
    const float4* xs4 = (const float4*)(x3 + (size_t)s * DD);
    const float4* xd4 = (const float4*)(x3 + (size_t)d * DD);
    const float4* ea4 = (const float4*)(eattr + (size_t)e * EFF);
    float acc[DD];
#pragma unroll
    for (int j = 0; j < DD; j++) acc[j] = s_b1[j];
#pragma unroll
    for (int c = 0; c < 8; c++) mlp_chunk(xs4[c], s_w1 + c * 4 * DD, acc);
#pragma unroll
    for (int c = 0; c < 8; c++) mlp_chunk(xd4[c], s_w1 + (DD + c * 4) * DD, acc);
#pragma unroll
    for (int c = 0; c < 4; c++) mlp_chunk(ea4[c], s_w1 + (2 * DD + c * 4) * DD, acc);
    float p = b2v;
#pragma unroll
    for (int j = 0; j < DD; j++) p += fmaxf(acc[j], 0.f) * s_w2[j];
    out[e] = p;
}

extern "C" void kernel_launch(void* const* d_in, const int* in_sizes, int n_in,
                              void* d_out, int out_size, void* d_ws, size_t ws_size,
                              hipStream_t stream) {
    const int E = in_sizes[0] / 2;
    const int N = in_sizes[2] / DD;

    const int* src = (const int*)d_in[0];
    const int* dst = src + E;
    const float* edge_attr = (const float*)d_in[1];
    const float* node_emb = (const float*)d_in[2];
    const float* sage1_wl = (const float*)d_in[3];
    const float* sage1_bl = (const float*)d_in[4];
    const float* sage1_wr = (const float*)d_in[5];
    const float* sage2_wl = (const float*)d_in[6];
    const float* sage2_bl = (const float*)d_in[7];
    const float* sage2_wr = (const float*)d_in[8];
    const float* gat_w = (const float*)d_in[9];
    const float* gat_att_src = (const float*)d_in[10];
    const float* gat_att_dst = (const float*)d_in[11];
    const float* gat_bias = (const float*)d_in[12];
    const float* mlp_w1 = (const float*)d_in[13];
    const float* mlp_b1 = (const float*)d_in[14];
    const float* mlp_w2 = (const float*)d_in[15];
    const float* mlp_b2 = (const float*)d_in[16];
    float* out = (float*)d_out;

    // Workspace layout
    char* ws = (char*)d_ws;
    int* deg = (int*)ws;                            // N (hist, then reused as fill ctr)
    int* rowptr = deg + N;                          // N+1
    int* csr_src = rowptr + (N + 1);                // E
    float* x1 = (float*)(csr_src + E);              // 32N
    float* x2 = x1 + (size_t)32 * N;                // 32N
    float* xh = x2 + (size_t)32 * N;                // 64N
    float* a_s = xh + (size_t)64 * N;               // 2N
    float* a_d = a_s + (size_t)2 * N;               // 2N
    float* x3 = a_d + (size_t)2 * N;                // 32N

    const int BS = 256;
    const int gE = (E + BS - 1) / BS;
    const int gN32 = (N * 32 + BS - 1) / BS;
    const int gN64 = (N * 64 + BS - 1) / BS;
    const int gN2 = (N * 2 + BS - 1) / BS;

    // ---- CSR build ----
    hipMemsetAsync(deg, 0, (size_t)N * sizeof(int), stream);
    hist_k<<<gE, BS, 0, stream>>>(dst, deg, E);
    scan_k<<<1, 1024, 0, stream>>>(deg, rowptr, N);
    hipMemsetAsync(deg, 0, (size_t)N * sizeof(int), stream);
    fill_k<<<gE, BS, 0, stream>>>(src, dst, rowptr, deg, csr_src, E);

    // ---- SAGE layers ----
    sage_fused_k<<<gN32, BS, 0, stream>>>(node_emb, rowptr, csr_src, sage1_wl, sage1_bl,
                                          sage1_wr, x1, N);
    sage_fused_k<<<gN32, BS, 0, stream>>>(x1, rowptr, csr_src, sage2_wl, sage2_bl,
                                          sage2_wr, x2, N);

    // ---- GAT ----
    gat_xh_k<<<gN64, BS, 0, stream>>>(x2, gat_w, xh, N);
    gat_scores_k<<<gN2, BS, 0, stream>>>(xh, gat_att_src, gat_att_dst, a_s, a_d, N);
    gat_fused_k<<<gN64, BS, 0, stream>>>(xh, a_s, a_d, rowptr, csr_src, gat_bias, x3, N);

    // ---- Edge MLP ----
    edge_mlp_v2<<<gE, BS, 0, stream>>>(x3, edge_attr, src, dst, mlp_w1, mlp_b1, mlp_w2,
                                       mlp_b2, out, E);
}

// Round 3
// 752.582 us; speedup vs baseline: 2.5808x; 1.2387x over previous
//
#include <hip/hip_runtime.h>
#include <hip/hip_fp16.h>

// GraphSAGE_GAT: SAGE(mean)x2 -> GAT(2 heads, softmax) -> edge MLP
// N=100000 nodes, E=1600000 edges, D=32, H=2, EF=16.
// R3: fp16 gather tables (x0/x1/x2, xh, Ps/Pd); factorized edge MLP
//     (per-node Ps/Pd precompute); parallel 3-phase scan; fused gat_xh+scores.

#define DD 32
#define HH 2
#define EFF 16

__device__ __forceinline__ float lrelu(float x) { return x > 0.f ? x : 0.2f * x; }

// ---- CSR build: histogram of dst ----
__global__ void hist_k(const int* __restrict__ dst, int* __restrict__ deg, int E) {
    int e = blockIdx.x * blockDim.x + threadIdx.x;
    if (e < E) atomicAdd(&deg[dst[e]], 1);
}

// ---- scan phase 1: per-1024-chunk exclusive scan + chunk totals ----
__global__ void scan1_k(const int* __restrict__ deg, int* __restrict__ rowptr,
                        int* __restrict__ blockSums, int N) {
    __shared__ int s_s[256];
    int blk = blockIdx.x, t = threadIdx.x;
    int base = blk * 1024 + t * 4;
    int v[4];
    int s = 0;
#pragma unroll
    for (int i = 0; i < 4; i++) {
        v[i] = (base + i < N) ? deg[base + i] : 0;
        s += v[i];
    }
    s_s[t] = s;
    __syncthreads();
    for (int off = 1; off < 256; off <<= 1) {
        int x = (t >= off) ? s_s[t - off] : 0;
        __syncthreads();
        s_s[t] += x;
        __syncthreads();
    }
    int excl = s_s[t] - s;
#pragma unroll
    for (int i = 0; i < 4; i++) {
        if (base + i < N) rowptr[base + i] = excl;
        excl += v[i];
    }
    if (t == 255) blockSums[blk] = s_s[255];
}

// ---- scan phase 2: scan the chunk totals (<=128 chunks) ----
__global__ void scan2_k(int* __restrict__ blockSums, int* __restrict__ rowptrN, int NB) {
    __shared__ int s_s[128];
    int t = threadIdx.x;
    int v = (t < NB) ? blockSums[t] : 0;
    s_s[t] = v;
    __syncthreads();
    for (int off = 1; off < 128; off <<= 1) {
        int x = (t >= off) ? s_s[t - off] : 0;
        __syncthreads();
        s_s[t] += x;
        __syncthreads();
    }
    if (t < NB) blockSums[t] = s_s[t] - v;  // exclusive
    if (t == 127) *rowptrN = s_s[127];      // total = E
}

// ---- scan phase 3: add chunk offsets ----
__global__ void scan3_k(int* __restrict__ rowptr, const int* __restrict__ blockSums, int N) {
    int i = blockIdx.x * blockDim.x + threadIdx.x;
    if (i < N) rowptr[i] += blockSums[i >> 10];
}

// ---- CSR build: scatter src ids into per-dst buckets ----
__global__ void fill_k(const int* __restrict__ src, const int* __restrict__ dst,
                       const int* __restrict__ rowptr, int* __restrict__ fill,
                       int* __restrict__ csr_src, int E) {
    int e = blockIdx.x * blockDim.x + threadIdx.x;
    if (e >= E) return;
    int d = dst[e];
    int pos = rowptr[d] + atomicAdd(&fill[d], 1);
    csr_src[pos] = src[e];
}

// ---- convert fp32 -> fp16 ----
__global__ void cvt_k(const float* __restrict__ in, __half* __restrict__ out, int n) {
    int i = blockIdx.x * blockDim.x + threadIdx.x;
    if (i < n) out[i] = __float2half(in[i]);
}

// ---- SAGE fused: gather-mean (fp16 x) + lin_l + lin_r + relu -> fp16 out ----
// one 32-lane group per node
__global__ void sage_fused16(const __half* __restrict__ x, const int* __restrict__ rowptr,
                             const int* __restrict__ csr_src, const float* __restrict__ wl,
                             const float* __restrict__ bl, const float* __restrict__ wr,
                             __half* __restrict__ out, int N) {
    __shared__ float s_wl[DD * DD];
    __shared__ float s_wr[DD * DD];
    __shared__ float s_b[DD];
    for (int i = threadIdx.x; i < DD * DD; i += blockDim.x) {
        s_wl[i] = wl[i];
        s_wr[i] = wr[i];
    }
    if (threadIdx.x < DD) s_b[threadIdx.x] = bl[threadIdx.x];
    __syncthreads();
    int gid = blockIdx.x * blockDim.x + threadIdx.x;
    int n = gid >> 5;
    if (n >= N) return;
    int k = gid & 31;
    int lo = rowptr[n], hi = rowptr[n + 1];
    float acc = 0.f;
    for (int j = lo; j < hi; j++) {
        int s = csr_src[j];
        acc += __half2float(x[(size_t)s * DD + k]);
    }
    float inv = 1.0f / fmaxf((float)(hi - lo), 1.0f);
    float mean = acc * inv;
    float xv = __half2float(x[(size_t)n * DD + k]);
    float o = s_b[k];
#pragma unroll
    for (int i = 0; i < DD; i++) {
        o += __shfl(mean, i, 32) * s_wl[i * DD + k];
        o += __shfl(xv, i, 32) * s_wr[i * DD + k];
    }
    out[(size_t)n * DD + k] = __float2half(fmaxf(o, 0.f));
}

// ---- GAT: xh = x @ gat_w (fp16 out) + per-node scores a_s, a_d (fused) ----
// one wave64 per node: lane j computes xh[n, j]; head h = j>>5
__global__ void gat_xh_scores_k(const __half* __restrict__ x, const float* __restrict__ w,
                                const float* __restrict__ att_src,
                                const float* __restrict__ att_dst, __half* __restrict__ xh,
                                float* __restrict__ a_s, float* __restrict__ a_d, int N) {
    __shared__ float s_w[DD * HH * DD];  // 32x64
    for (int i = threadIdx.x; i < DD * HH * DD; i += blockDim.x) s_w[i] = w[i];
    __syncthreads();
    int gid = blockIdx.x * blockDim.x + threadIdx.x;
    int n = gid >> 6;
    if (n >= N) return;
    int j = gid & 63;
    int h = j >> 5, kk = j & 31;
    float xv = __half2float(x[(size_t)n * DD + kk]);
    float acc = 0.f;
#pragma unroll
    for (int i = 0; i < DD; i++) acc += __shfl(xv, i, 32) * s_w[i * (HH * DD) + j];
    xh[(size_t)n * (HH * DD) + j] = __float2half(acc);
    float pa = acc * att_src[h * DD + kk];
    float pd = acc * att_dst[h * DD + kk];
#pragma unroll
    for (int off = 16; off > 0; off >>= 1) {
        pa += __shfl_xor(pa, off, 32);
        pd += __shfl_xor(pd, off, 32);
    }
    if (kk == 0) {
        a_s[n * HH + h] = pa;
        a_d[n * HH + h] = pd;
    }
}

// ---- GAT fused: online softmax over incoming edges (+self loop), one wave/node ----
__global__ void gat_fused16(const __half* __restrict__ xh, const float* __restrict__ a_s,
                            const float* __restrict__ a_d, const int* __restrict__ rowptr,
                            const int* __restrict__ csr_src, const float* __restrict__ bias,
                            float* __restrict__ out, int N) {
    int gid = blockIdx.x * blockDim.x + threadIdx.x;
    int n = gid >> 6;
    if (n >= N) return;
    int l = gid & 63;
    int h = l >> 5, kk = l & 31;
    float ad = a_d[n * HH + h];
    float m = lrelu(a_s[n * HH + h] + ad);  // self loop
    float den = 1.f;
    float acc = __half2float(xh[(size_t)n * (HH * DD) + l]);
    int lo = rowptr[n], hi = rowptr[n + 1];
    for (int j = lo; j < hi; j++) {
        int s = csr_src[j];
        float alpha = lrelu(a_s[s * HH + h] + ad);
        float nm = fmaxf(m, alpha);
        float scale = __expf(m - nm);
        float w = __expf(alpha - nm);
        den = den * scale + w;
        acc = acc * scale + w * __half2float(xh[(size_t)s * (HH * DD) + l]);
        m = nm;
    }
    float v = acc / (den + 1e-16f);
    float o = 0.5f * (v + __shfl_xor(v, 32, 64));
    if (h == 0) out[(size_t)n * DD + kk] = fmaxf(o + bias[kk], 0.f);
}

// ---- Edge-MLP precompute: Ps[n] = W1s^T x3[n] + b1, Pd[n] = W1d^T x3[n] (fp16) ----
// one wave64 per node: lanes 0-31 -> Ps, 32-63 -> Pd
__global__ void mlp_pre_k(const float* __restrict__ x3, const float* __restrict__ w1,
                          const float* __restrict__ b1, __half* __restrict__ Ps,
                          __half* __restrict__ Pd, int N) {
    __shared__ float s_w[2 * DD * DD];  // rows 0..63 of w1
    __shared__ float s_b[DD];
    for (int i = threadIdx.x; i < 2 * DD * DD; i += blockDim.x) s_w[i] = w1[i];
    if (threadIdx.x < DD) s_b[threadIdx.x] = b1[threadIdx.x];
    __syncthreads();
    int gid = blockIdx.x * blockDim.x + threadIdx.x;
    int n = gid >> 6;
    if (n >= N) return;
    int l = gid & 63;
    int which = l >> 5, j = l & 31;
    float xv = x3[(size_t)n * DD + j];
    float acc = which ? 0.f : s_b[j];
    const float* wb = s_w + which * DD * DD;
#pragma unroll
    for (int i = 0; i < DD; i++) acc += __shfl(xv, i, 32) * wb[i * DD + j];
    (which ? Pd : Ps)[(size_t)n * DD + j] = __float2half(acc);
}

// ---- Edge MLP v3: acc = Ps[s] + Pd[d] + W1e*ea; out = relu(acc) . w2 + b2 ----
__device__ __forceinline__ void add_half_row(const __half* __restrict__ row, float acc[DD]) {
    const uint4* r4 = (const uint4*)row;
#pragma unroll
    for (int c = 0; c < 4; c++) {
        uint4 u = r4[c];
        unsigned uu[4] = {u.x, u.y, u.z, u.w};
#pragma unroll
        for (int t = 0; t < 4; t++) {
            __half2 h2 = *reinterpret_cast<const __half2*>(&uu[t]);
            float2 f = __half22float2(h2);
            acc[c * 8 + t * 2 + 0] += f.x;
            acc[c * 8 + t * 2 + 1] += f.y;
        }
    }
}

__global__ void edge_mlp_v3(const __half* __restrict__ Ps, const __half* __restrict__ Pd,
                            const float* __restrict__ eattr, const int* __restrict__ src,
                            const int* __restrict__ dst, const float* __restrict__ w1e,
                            const float* __restrict__ w2, const float* __restrict__ b2,
                            float* __restrict__ out, int E) {
    __shared__ float s_we[EFF * DD];  // rows 64..79 of w1
    __shared__ float s_w2[DD];
    for (int i = threadIdx.x; i < EFF * DD; i += blockDim.x) s_we[i] = w1e[i];
    if (threadIdx.x < DD) s_w2[threadIdx.x] = w2[threadIdx.x];
    __syncthreads();
    int e = blockIdx.x * blockDim.x + threadIdx.x;
    if (e >= E) return;
    float b2v = b2[0];
    int s = src[e], d = dst[e];
    float acc[DD] = {};
    add_half_row(Ps + (size_t)s * DD, acc);
    add_half_row(Pd + (size_t)d * DD, acc);
    const float4* ea4 = (const float4*)(eattr + (size_t)e * EFF);
#pragma unroll
    for (int c = 0; c < 4; c++) {
        float4 v = ea4[c];
        const float va[4] = {v.x, v.y, v.z, v.w};
#pragma unroll
        for (int r = 0; r < 4; r++) {
#pragma unroll
            for (int j4 = 0; j4 < 8; j4++) {
                const float4 w = *(const float4*)(s_we + (c * 4 + r) * DD + j4 * 4);
                acc[j4 * 4 + 0] += va[r] * w.x;
                acc[j4 * 4 + 1] += va[r] * w.y;
                acc[j4 * 4 + 2] += va[r] * w.z;
                acc[j4 * 4 + 3] += va[r] * w.w;
            }
        }
    }
    float p = b2v;
#pragma unroll
    for (int j = 0; j < DD; j++) p += fmaxf(acc[j], 0.f) * s_w2[j];
    out[e] = p;
}

extern "C" void kernel_launch(void* const* d_in, const int* in_sizes, int n_in,
                              void* d_out, int out_size, void* d_ws, size_t ws_size,
                              hipStream_t stream) {
    const int E = in_sizes[0] / 2;
    const int N = in_sizes[2] / DD;

    const int* src = (const int*)d_in[0];
    const int* dst = src + E;
    const float* edge_attr = (const float*)d_in[1];
    const float* node_emb = (const float*)d_in[2];
    const float* sage1_wl = (const float*)d_in[3];
    const float* sage1_bl = (const float*)d_in[4];
    const float* sage1_wr = (const float*)d_in[5];
    const float* sage2_wl = (const float*)d_in[6];
    const float* sage2_bl = (const float*)d_in[7];
    const float* sage2_wr = (const float*)d_in[8];
    const float* gat_w = (const float*)d_in[9];
    const float* gat_att_src = (const float*)d_in[10];
    const float* gat_att_dst = (const float*)d_in[11];
    const float* gat_bias = (const float*)d_in[12];
    const float* mlp_w1 = (const float*)d_in[13];
    const float* mlp_b1 = (const float*)d_in[14];
    const float* mlp_w2 = (const float*)d_in[15];
    const float* mlp_b2 = (const float*)d_in[16];
    float* out = (float*)d_out;

    // Workspace layout (256B-aligned chunks)
    char* ws = (char*)d_ws;
    size_t off = 0;
    auto alloc = [&](size_t bytes) {
        char* p = ws + off;
        off = (off + bytes + 255) & ~(size_t)255;
        return p;
    };
    int* deg = (int*)alloc((size_t)N * 4);
    int* rowptr = (int*)alloc((size_t)(N + 1) * 4);
    int* blockSums = (int*)alloc(128 * 4);
    int* csr_src = (int*)alloc((size_t)E * 4);
    __half* x0h = (__half*)alloc((size_t)N * DD * 2);
    __half* x1h = (__half*)alloc((size_t)N * DD * 2);
    __half* x2h = (__half*)alloc((size_t)N * DD * 2);
    __half* xh16 = (__half*)alloc((size_t)N * HH * DD * 2);
    float* a_s = (float*)alloc((size_t)N * HH * 4);
    float* a_d = (float*)alloc((size_t)N * HH * 4);
    float* x3 = (float*)alloc((size_t)N * DD * 4);
    __half* Ps = (__half*)alloc((size_t)N * DD * 2);
    __half* Pd = (__half*)alloc((size_t)N * DD * 2);

    const int BS = 256;
    const int gE = (E + BS - 1) / BS;
    const int gN32 = (N * 32 + BS - 1) / BS;
    const int gN64 = (N * 64 + BS - 1) / BS;
    const int NB = (N + 1023) / 1024;

    // ---- CSR build ----
    hipMemsetAsync(deg, 0, (size_t)N * sizeof(int), stream);
    hist_k<<<gE, BS, 0, stream>>>(dst, deg, E);
    scan1_k<<<NB, 256, 0, stream>>>(deg, rowptr, blockSums, N);
    scan2_k<<<1, 128, 0, stream>>>(blockSums, rowptr + N, NB);
    scan3_k<<<(N + BS - 1) / BS, BS, 0, stream>>>(rowptr, blockSums, N);
    hipMemsetAsync(deg, 0, (size_t)N * sizeof(int), stream);
    fill_k<<<gE, BS, 0, stream>>>(src, dst, rowptr, deg, csr_src, E);

    // ---- fp16 input conversion ----
    cvt_k<<<gN32, BS, 0, stream>>>(node_emb, x0h, N * DD);

    // ---- SAGE layers ----
    sage_fused16<<<gN32, BS, 0, stream>>>(x0h, rowptr, csr_src, sage1_wl, sage1_bl,
                                          sage1_wr, x1h, N);
    sage_fused16<<<gN32, BS, 0, stream>>>(x1h, rowptr, csr_src, sage2_wl, sage2_bl,
                                          sage2_wr, x2h, N);

    // ---- GAT ----
    gat_xh_scores_k<<<gN64, BS, 0, stream>>>(x2h, gat_w, gat_att_src, gat_att_dst, xh16,
                                             a_s, a_d, N);
    gat_fused16<<<gN64, BS, 0, stream>>>(xh16, a_s, a_d, rowptr, csr_src, gat_bias, x3, N);

    // ---- Edge MLP ----
    mlp_pre_k<<<gN64, BS, 0, stream>>>(x3, mlp_w1, mlp_b1, Ps, Pd, N);
    edge_mlp_v3<<<gE, BS, 0, stream>>>(Ps, Pd, edge_attr, src, dst, mlp_w1 + 2 * DD * DD,
                                       mlp_w2, mlp_b2, out, E);
}

// Round 4
// 634.226 us; speedup vs baseline: 3.0624x; 1.1866x over previous
//
#include <hip/hip_runtime.h>
#include <hip/hip_fp16.h>

// GraphSAGE_GAT: SAGE(mean)x2 -> GAT(2 heads, softmax) -> edge MLP
// N=100000, E=1600000, D=32, H=2, EF=16.
// R4: GAT exact-max precompute (lrelu monotone) -> exp out of carried chain;
//     GAT aggregates in x2-space (64B/edge gather, no xh buffer);
//     mlp-pre fused into GAT epilogue (no x3 buffer); SAGE gather unroll x4.

#define DD 32
#define HH 2
#define EFF 16

__device__ __forceinline__ float lrelu(float x) { return x > 0.f ? x : 0.2f * x; }

// ---- CSR build: histogram of dst ----
__global__ void hist_k(const int* __restrict__ dst, int* __restrict__ deg, int E) {
    int e = blockIdx.x * blockDim.x + threadIdx.x;
    if (e < E) atomicAdd(&deg[dst[e]], 1);
}

// ---- scan phase 1: per-1024-chunk exclusive scan + chunk totals ----
__global__ void scan1_k(const int* __restrict__ deg, int* __restrict__ rowptr,
                        int* __restrict__ blockSums, int N) {
    __shared__ int s_s[256];
    int blk = blockIdx.x, t = threadIdx.x;
    int base = blk * 1024 + t * 4;
    int v[4];
    int s = 0;
#pragma unroll
    for (int i = 0; i < 4; i++) {
        v[i] = (base + i < N) ? deg[base + i] : 0;
        s += v[i];
    }
    s_s[t] = s;
    __syncthreads();
    for (int off = 1; off < 256; off <<= 1) {
        int x = (t >= off) ? s_s[t - off] : 0;
        __syncthreads();
        s_s[t] += x;
        __syncthreads();
    }
    int excl = s_s[t] - s;
#pragma unroll
    for (int i = 0; i < 4; i++) {
        if (base + i < N) rowptr[base + i] = excl;
        excl += v[i];
    }
    if (t == 255) blockSums[blk] = s_s[255];
}

// ---- scan phase 2: scan the chunk totals (<=128 chunks) ----
__global__ void scan2_k(int* __restrict__ blockSums, int* __restrict__ rowptrN, int NB) {
    __shared__ int s_s[128];
    int t = threadIdx.x;
    int v = (t < NB) ? blockSums[t] : 0;
    s_s[t] = v;
    __syncthreads();
    for (int off = 1; off < 128; off <<= 1) {
        int x = (t >= off) ? s_s[t - off] : 0;
        __syncthreads();
        s_s[t] += x;
        __syncthreads();
    }
    if (t < NB) blockSums[t] = s_s[t] - v;  // exclusive
    if (t == 127) *rowptrN = s_s[127];      // total = E
}

// ---- scan phase 3: add chunk offsets ----
__global__ void scan3_k(int* __restrict__ rowptr, const int* __restrict__ blockSums, int N) {
    int i = blockIdx.x * blockDim.x + threadIdx.x;
    if (i < N) rowptr[i] += blockSums[i >> 10];
}

// ---- CSR build: scatter src ids into per-dst buckets ----
__global__ void fill_k(const int* __restrict__ src, const int* __restrict__ dst,
                       const int* __restrict__ rowptr, int* __restrict__ fill,
                       int* __restrict__ csr_src, int E) {
    int e = blockIdx.x * blockDim.x + threadIdx.x;
    if (e >= E) return;
    int d = dst[e];
    int pos = rowptr[d] + atomicAdd(&fill[d], 1);
    csr_src[pos] = src[e];
}

// ---- convert fp32 -> fp16 ----
__global__ void cvt_k(const float* __restrict__ in, __half* __restrict__ out, int n) {
    int i = blockIdx.x * blockDim.x + threadIdx.x;
    if (i < n) out[i] = __float2half(in[i]);
}

// ---- SAGE fused: gather-mean (x4 unrolled) + lin_l + lin_r + relu -> fp16 ----
// one 32-lane group per node
__global__ void sage_fused16(const __half* __restrict__ x, const int* __restrict__ rowptr,
                             const int* __restrict__ csr_src, const float* __restrict__ wl,
                             const float* __restrict__ bl, const float* __restrict__ wr,
                             __half* __restrict__ out, int N) {
    __shared__ float s_wl[DD * DD];
    __shared__ float s_wr[DD * DD];
    __shared__ float s_b[DD];
    for (int i = threadIdx.x; i < DD * DD; i += blockDim.x) {
        s_wl[i] = wl[i];
        s_wr[i] = wr[i];
    }
    if (threadIdx.x < DD) s_b[threadIdx.x] = bl[threadIdx.x];
    __syncthreads();
    int gid = blockIdx.x * blockDim.x + threadIdx.x;
    int n = gid >> 5;
    if (n >= N) return;
    int k = gid & 31;
    int lo = rowptr[n], hi = rowptr[n + 1];
    float a0 = 0.f, a1 = 0.f, a2 = 0.f, a3 = 0.f;
    int j = lo;
    for (; j + 3 < hi; j += 4) {
        int s0 = csr_src[j], s1 = csr_src[j + 1], s2 = csr_src[j + 2], s3 = csr_src[j + 3];
        a0 += __half2float(x[s0 * DD + k]);
        a1 += __half2float(x[s1 * DD + k]);
        a2 += __half2float(x[s2 * DD + k]);
        a3 += __half2float(x[s3 * DD + k]);
    }
    for (; j < hi; j++) a0 += __half2float(x[csr_src[j] * DD + k]);
    float acc = (a0 + a1) + (a2 + a3);
    float inv = 1.0f / fmaxf((float)(hi - lo), 1.0f);
    float mean = acc * inv;
    float xv = __half2float(x[n * DD + k]);
    float o = s_b[k];
#pragma unroll
    for (int i = 0; i < DD; i++) {
        o += __shfl(mean, i, 32) * s_wl[i * DD + k];
        o += __shfl(xv, i, 32) * s_wr[i * DD + k];
    }
    out[n * DD + k] = __float2half(fmaxf(o, 0.f));
}

// ---- GAT scores only: a_s[n,h], a_d[n,h] from x2 @ W (xh never stored) ----
// one wave64 per node
__global__ void gat_scores_k(const __half* __restrict__ x, const float* __restrict__ w,
                             const float* __restrict__ att_src,
                             const float* __restrict__ att_dst, float* __restrict__ a_s,
                             float* __restrict__ a_d, int N) {
    __shared__ float s_w[DD * HH * DD];  // 32x64
    for (int i = threadIdx.x; i < DD * HH * DD; i += blockDim.x) s_w[i] = w[i];
    __syncthreads();
    int gid = blockIdx.x * blockDim.x + threadIdx.x;
    int n = gid >> 6;
    if (n >= N) return;
    int j = gid & 63;
    int h = j >> 5, kk = j & 31;
    float xv = __half2float(x[n * DD + kk]);
    float acc = 0.f;
#pragma unroll
    for (int i = 0; i < DD; i++) acc += __shfl(xv, i, 32) * s_w[i * (HH * DD) + j];
    float pa = acc * att_src[h * DD + kk];
    float pd = acc * att_dst[h * DD + kk];
#pragma unroll
    for (int off = 16; off > 0; off >>= 1) {
        pa += __shfl_xor(pa, off, 32);
        pd += __shfl_xor(pd, off, 32);
    }
    if (kk == 0) {
        a_s[n * HH + h] = pa;
        a_d[n * HH + h] = pd;
    }
}

// ---- GAT fused v3: exact max (lrelu monotone) -> chain-free weighted sum in
//      x2-space -> dense W transform -> head-mean+bias+relu -> fused mlp-pre ----
// one wave64 per node; lanes h=0 write Ps, h=1 write Pd
__global__ void gat_fused_v3(const __half* __restrict__ x2, const float* __restrict__ a_s,
                             const float* __restrict__ a_d, const int* __restrict__ rowptr,
                             const int* __restrict__ csr_src, const float* __restrict__ gw,
                             const float* __restrict__ bias, const float* __restrict__ w1,
                             const float* __restrict__ b1, __half* __restrict__ Ps,
                             __half* __restrict__ Pd, int N) {
    __shared__ float s_gw[DD * HH * DD];  // gat W: 32 x 64
    __shared__ float s_w1[2 * DD * DD];   // mlp w1 rows 0..63
    __shared__ float s_b1[DD];
    __shared__ float s_bias[DD];
    int t = threadIdx.x;
    for (int i = t; i < DD * HH * DD; i += blockDim.x) s_gw[i] = gw[i];
    for (int i = t; i < 2 * DD * DD; i += blockDim.x) s_w1[i] = w1[i];
    if (t < DD) {
        s_b1[t] = b1[t];
        s_bias[t] = bias[t];
    }
    __syncthreads();
    int gid = blockIdx.x * blockDim.x + t;
    int n = gid >> 6;
    if (n >= N) return;
    int l = gid & 63;
    int h = l >> 5, kk = l & 31;
    int lo = rowptr[n], hi = rowptr[n + 1];
    float ad = a_d[n * HH + h];
    float as_self = a_s[n * HH + h];
    // phase 1: exact segment max of a_s (lanes parallel over edges)
    float mx = as_self;
    for (int j = lo + kk; j < hi; j += 32) mx = fmaxf(mx, a_s[csr_src[j] * HH + h]);
#pragma unroll
    for (int off = 16; off > 0; off >>= 1) mx = fmaxf(mx, __shfl_xor(mx, off, 32));
    float m = lrelu(mx + ad);
    // phase 2: weighted sum in x2-space, exp independent per edge, unroll x2
    float wself = __expf(lrelu(as_self + ad) - m);
    float den0 = wself, den1 = 0.f;
    float y0 = wself * __half2float(x2[n * DD + kk]);
    float y1 = 0.f;
    int j = lo;
    for (; j + 1 < hi; j += 2) {
        int s0 = csr_src[j], s1 = csr_src[j + 1];
        float w0 = __expf(lrelu(a_s[s0 * HH + h] + ad) - m);
        float w1v = __expf(lrelu(a_s[s1 * HH + h] + ad) - m);
        den0 += w0;
        den1 += w1v;
        y0 += w0 * __half2float(x2[s0 * DD + kk]);
        y1 += w1v * __half2float(x2[s1 * DD + kk]);
    }
    if (j < hi) {
        int s0 = csr_src[j];
        float w0 = __expf(lrelu(a_s[s0 * HH + h] + ad) - m);
        den0 += w0;
        y0 += w0 * __half2float(x2[s0 * DD + kk]);
    }
    float den = den0 + den1;
    float y = y0 + y1;
    // transform to head-output space: v_l = (y_h @ Wg)[l] / den
    float v = 0.f;
#pragma unroll
    for (int i = 0; i < DD; i++) v += __shfl(y, i, 32) * s_gw[i * (HH * DD) + l];
    v /= (den + 1e-16f);
    // mean over heads + bias + relu (identical on both halves)
    float o = fmaxf(0.5f * (v + __shfl_xor(v, 32, 64)) + s_bias[kk], 0.f);
    // fused mlp-pre: h=0 -> Ps (rows 0..31 of w1, +b1), h=1 -> Pd (rows 32..63)
    float p = h ? 0.f : s_b1[kk];
    const float* wb = s_w1 + h * DD * DD;
#pragma unroll
    for (int i = 0; i < DD; i++) p += __shfl(o, i, 32) * wb[i * DD + kk];
    (h ? Pd : Ps)[n * DD + kk] = __float2half(p);
}

// ---- Edge MLP: acc = Ps[s] + Pd[d] + W1e*ea; out = relu(acc) . w2 + b2 ----
__device__ __forceinline__ void add_half_row(const __half* __restrict__ row, float acc[DD]) {
    const uint4* r4 = (const uint4*)row;
#pragma unroll
    for (int c = 0; c < 4; c++) {
        uint4 u = r4[c];
        unsigned uu[4] = {u.x, u.y, u.z, u.w};
#pragma unroll
        for (int t = 0; t < 4; t++) {
            __half2 h2 = *reinterpret_cast<const __half2*>(&uu[t]);
            float2 f = __half22float2(h2);
            acc[c * 8 + t * 2 + 0] += f.x;
            acc[c * 8 + t * 2 + 1] += f.y;
        }
    }
}

__global__ void edge_mlp_v3(const __half* __restrict__ Ps, const __half* __restrict__ Pd,
                            const float* __restrict__ eattr, const int* __restrict__ src,
                            const int* __restrict__ dst, const float* __restrict__ w1e,
                            const float* __restrict__ w2, const float* __restrict__ b2,
                            float* __restrict__ out, int E) {
    __shared__ float s_we[EFF * DD];  // rows 64..79 of w1
    __shared__ float s_w2[DD];
    for (int i = threadIdx.x; i < EFF * DD; i += blockDim.x) s_we[i] = w1e[i];
    if (threadIdx.x < DD) s_w2[threadIdx.x] = w2[threadIdx.x];
    __syncthreads();
    int e = blockIdx.x * blockDim.x + threadIdx.x;
    if (e >= E) return;
    float b2v = b2[0];
    int s = src[e], d = dst[e];
    float acc[DD] = {};
    add_half_row(Ps + (size_t)s * DD, acc);
    add_half_row(Pd + (size_t)d * DD, acc);
    const float4* ea4 = (const float4*)(eattr + (size_t)e * EFF);
#pragma unroll
    for (int c = 0; c < 4; c++) {
        float4 v = ea4[c];
        const float va[4] = {v.x, v.y, v.z, v.w};
#pragma unroll
        for (int r = 0; r < 4; r++) {
#pragma unroll
            for (int j4 = 0; j4 < 8; j4++) {
                const float4 w = *(const float4*)(s_we + (c * 4 + r) * DD + j4 * 4);
                acc[j4 * 4 + 0] += va[r] * w.x;
                acc[j4 * 4 + 1] += va[r] * w.y;
                acc[j4 * 4 + 2] += va[r] * w.z;
                acc[j4 * 4 + 3] += va[r] * w.w;
            }
        }
    }
    float p = b2v;
#pragma unroll
    for (int j = 0; j < DD; j++) p += fmaxf(acc[j], 0.f) * s_w2[j];
    out[e] = p;
}

extern "C" void kernel_launch(void* const* d_in, const int* in_sizes, int n_in,
                              void* d_out, int out_size, void* d_ws, size_t ws_size,
                              hipStream_t stream) {
    const int E = in_sizes[0] / 2;
    const int N = in_sizes[2] / DD;

    const int* src = (const int*)d_in[0];
    const int* dst = src + E;
    const float* edge_attr = (const float*)d_in[1];
    const float* node_emb = (const float*)d_in[2];
    const float* sage1_wl = (const float*)d_in[3];
    const float* sage1_bl = (const float*)d_in[4];
    const float* sage1_wr = (const float*)d_in[5];
    const float* sage2_wl = (const float*)d_in[6];
    const float* sage2_bl = (const float*)d_in[7];
    const float* sage2_wr = (const float*)d_in[8];
    const float* gat_w = (const float*)d_in[9];
    const float* gat_att_src = (const float*)d_in[10];
    const float* gat_att_dst = (const float*)d_in[11];
    const float* gat_bias = (const float*)d_in[12];
    const float* mlp_w1 = (const float*)d_in[13];
    const float* mlp_b1 = (const float*)d_in[14];
    const float* mlp_w2 = (const float*)d_in[15];
    const float* mlp_b2 = (const float*)d_in[16];
    float* out = (float*)d_out;

    // Workspace layout (256B-aligned chunks)
    char* ws = (char*)d_ws;
    size_t off = 0;
    auto alloc = [&](size_t bytes) {
        char* p = ws + off;
        off = (off + bytes + 255) & ~(size_t)255;
        return p;
    };
    int* deg = (int*)alloc((size_t)N * 4);
    int* rowptr = (int*)alloc((size_t)(N + 1) * 4);
    int* blockSums = (int*)alloc(128 * 4);
    int* csr_src = (int*)alloc((size_t)E * 4);
    __half* x0h = (__half*)alloc((size_t)N * DD * 2);
    __half* x1h = (__half*)alloc((size_t)N * DD * 2);
    __half* x2h = (__half*)alloc((size_t)N * DD * 2);
    float* a_s = (float*)alloc((size_t)N * HH * 4);
    float* a_d = (float*)alloc((size_t)N * HH * 4);
    __half* Ps = (__half*)alloc((size_t)N * DD * 2);
    __half* Pd = (__half*)alloc((size_t)N * DD * 2);

    const int BS = 256;
    const int gE = (E + BS - 1) / BS;
    const int gN32 = (N * 32 + BS - 1) / BS;
    const int gN64 = (N * 64 + BS - 1) / BS;
    const int NB = (N + 1023) / 1024;

    // ---- CSR build ----
    hipMemsetAsync(deg, 0, (size_t)N * sizeof(int), stream);
    hist_k<<<gE, BS, 0, stream>>>(dst, deg, E);
    scan1_k<<<NB, 256, 0, stream>>>(deg, rowptr, blockSums, N);
    scan2_k<<<1, 128, 0, stream>>>(blockSums, rowptr + N, NB);
    scan3_k<<<(N + BS - 1) / BS, BS, 0, stream>>>(rowptr, blockSums, N);
    hipMemsetAsync(deg, 0, (size_t)N * sizeof(int), stream);
    fill_k<<<gE, BS, 0, stream>>>(src, dst, rowptr, deg, csr_src, E);

    // ---- fp16 input conversion ----
    cvt_k<<<gN32, BS, 0, stream>>>(node_emb, x0h, N * DD);

    // ---- SAGE layers ----
    sage_fused16<<<gN32, BS, 0, stream>>>(x0h, rowptr, csr_src, sage1_wl, sage1_bl,
                                          sage1_wr, x1h, N);
    sage_fused16<<<gN32, BS, 0, stream>>>(x1h, rowptr, csr_src, sage2_wl, sage2_bl,
                                          sage2_wr, x2h, N);

    // ---- GAT (+ fused mlp-pre) ----
    gat_scores_k<<<gN64, BS, 0, stream>>>(x2h, gat_w, gat_att_src, gat_att_dst, a_s, a_d, N);
    gat_fused_v3<<<gN64, BS, 0, stream>>>(x2h, a_s, a_d, rowptr, csr_src, gat_w, gat_bias,
                                          mlp_w1, mlp_b1, Ps, Pd, N);

    // ---- Edge MLP ----
    edge_mlp_v3<<<gE, BS, 0, stream>>>(Ps, Pd, edge_attr, src, dst, mlp_w1 + 2 * DD * DD,
                                       mlp_w2, mlp_b2, out, E);
}